// Round 6
// baseline (559.874 us; speedup 1.0000x reference)
//
#include <hip/hip_runtime.h>
#include <hip/hip_bf16.h>

#define HIDDEN 896
#define HEADS 7
#define HDIM 128
#define BB 4
#define TT 2048
#define MTOT (BB*TT)   // 8192

typedef short bf16x8 __attribute__((ext_vector_type(8)));
typedef float f32x4 __attribute__((ext_vector_type(4)));

__device__ __forceinline__ short f2bf(float f) {
    union { float f; unsigned u; } v; v.f = f;
    unsigned r = (v.u + 0x7FFF + ((v.u >> 16) & 1)) >> 16;
    return (short)r;
}

// ---------------- kernel 1: cast x (fp32) -> bf16 ----------------
__global__ __launch_bounds__(256) void cast_x_kernel(const float* __restrict__ x,
                                                     short* __restrict__ xb) {
    int base = (blockIdx.x * 256 + threadIdx.x) * 4;
    if (base < MTOT * HIDDEN) {
        float4 v = *(const float4*)(x + base);
        short4 o;
        o.x = f2bf(v.x); o.y = f2bf(v.y); o.z = f2bf(v.z); o.w = f2bf(v.w);
        *(short4*)(xb + base) = o;
    }
}

// cast Wo fp32[896][896] -> bf16 (already B^T form [n][k])
__global__ __launch_bounds__(256) void cast_wo_kernel(const float* __restrict__ src,
                                                      short* __restrict__ dst) {
    int base = (blockIdx.x * 256 + threadIdx.x) * 4;
    if (base < HIDDEN * HIDDEN) {
        float4 v = *(const float4*)(src + base);
        short4 o;
        o.x = f2bf(v.x); o.y = f2bf(v.y); o.z = f2bf(v.z); o.w = f2bf(v.w);
        *(short4*)(dst + base) = o;
    }
}

// transpose-cast Wq/Wk/Wv fp32 [head][896 k][128 n] -> bf16 Wt[type*7+head][128 n][896 k]
__global__ __launch_bounds__(256) void transpose_cast_w(
    const float* __restrict__ Wq, const float* __restrict__ Wk,
    const float* __restrict__ Wv, short* __restrict__ Wt)
{
    __shared__ float tile[32][33];
    const int z = blockIdx.z;
    const int type = z / 7, head = z % 7;
    const float* src = (type == 0 ? Wq : (type == 1 ? Wk : Wv)) + head * (HIDDEN * HDIM);
    short* dst = Wt + (size_t)z * (HDIM * HIDDEN);
    const int r0 = blockIdx.x * 32, c0 = blockIdx.y * 32;
    const int tx = threadIdx.x & 31, ty = threadIdx.x >> 5;  // 32 x 8
    for (int i = 0; i < 4; i++)
        tile[ty * 4 + i][tx] = src[(r0 + ty * 4 + i) * HDIM + c0 + tx];
    __syncthreads();
    for (int i = 0; i < 4; i++)
        dst[(c0 + ty * 4 + i) * HIDDEN + r0 + tx] = f2bf(tile[tx][ty * 4 + i]);
}

// ---------------- kernel 2: QKV projection GEMM (128x128 tile) ----------------
__global__ __launch_bounds__(256) void qkv_gemm(
    const short* __restrict__ xb, const short* __restrict__ Wt,
    short* __restrict__ Q, short* __restrict__ Kk, short* __restrict__ Vt)
{
    __shared__ short Ash[128 * 40];
    __shared__ short Bsh[128 * 40];
    const int m0 = blockIdx.x * 128;
    const int z = blockIdx.y;
    const int head = z % 7, type = z / 7;
    const short* Wz = Wt + (size_t)z * (HDIM * HIDDEN);

    const int tid = threadIdx.x;
    const int wave = tid >> 6, lane = tid & 63;
    const int quad = lane >> 4, l16 = lane & 15;
    const int wm = (wave >> 1) * 64, wn = (wave & 1) * 64;

    f32x4 acc[4][4] = {};
    const int sr = tid >> 2, sc = (tid & 3) * 8;

    for (int k0 = 0; k0 < HIDDEN; k0 += 32) {
        bf16x8 a0 = *(const bf16x8*)(xb + (size_t)(m0 + sr) * HIDDEN + k0 + sc);
        bf16x8 a1 = *(const bf16x8*)(xb + (size_t)(m0 + sr + 64) * HIDDEN + k0 + sc);
        bf16x8 b0 = *(const bf16x8*)(Wz + (size_t)sr * HIDDEN + k0 + sc);
        bf16x8 b1 = *(const bf16x8*)(Wz + (size_t)(sr + 64) * HIDDEN + k0 + sc);
        __syncthreads();
        *(bf16x8*)(Ash + sr * 40 + sc) = a0;
        *(bf16x8*)(Ash + (sr + 64) * 40 + sc) = a1;
        *(bf16x8*)(Bsh + sr * 40 + sc) = b0;
        *(bf16x8*)(Bsh + (sr + 64) * 40 + sc) = b1;
        __syncthreads();
        bf16x8 af[4], bfr[4];
        for (int mi = 0; mi < 4; mi++)
            af[mi] = *(const bf16x8*)(Ash + (wm + mi * 16 + l16) * 40 + quad * 8);
        for (int ni = 0; ni < 4; ni++)
            bfr[ni] = *(const bf16x8*)(Bsh + (wn + ni * 16 + l16) * 40 + quad * 8);
        for (int mi = 0; mi < 4; mi++)
            for (int ni = 0; ni < 4; ni++)
                acc[mi][ni] = __builtin_amdgcn_mfma_f32_16x16x32_bf16(af[mi], bfr[ni], acc[mi][ni], 0, 0, 0);
    }

    const size_t base = (size_t)head * (MTOT * HDIM);
    if (type == 0) {
        // fold softmax scale AND log2(e) into Q (softmax done in exp2 domain)
        const float qs = 0.08838834764831845f * 1.4426950408889634f;
        for (int mi = 0; mi < 4; mi++)
            for (int ni = 0; ni < 4; ni++)
                for (int r = 0; r < 4; r++) {
                    int m = m0 + wm + mi * 16 + quad * 4 + r;
                    int n = wn + ni * 16 + l16;
                    Q[base + (size_t)m * HDIM + n] = f2bf(acc[mi][ni][r] * qs);
                }
    } else if (type == 1) {
        for (int mi = 0; mi < 4; mi++)
            for (int ni = 0; ni < 4; ni++)
                for (int r = 0; r < 4; r++) {
                    int m = m0 + wm + mi * 16 + quad * 4 + r;
                    int n = wn + ni * 16 + l16;
                    Kk[base + (size_t)m * HDIM + n] = f2bf(acc[mi][ni][r]);
                }
    } else {
        for (int mi = 0; mi < 4; mi++)
            for (int ni = 0; ni < 4; ni++) {
                int m = m0 + wm + mi * 16 + quad * 4;
                int bb = m >> 11, t = m & 2047;
                int n = wn + ni * 16 + l16;
                short4 o;
                o.x = f2bf(acc[mi][ni][0]); o.y = f2bf(acc[mi][ni][1]);
                o.z = f2bf(acc[mi][ni][2]); o.w = f2bf(acc[mi][ni][3]);
                *(short4*)(Vt + base + (size_t)bb * (HDIM * TT) + (size_t)n * TT + t) = o;
            }
    }
}

// ---------------- kernel 3: fano flash attention v6 (static-base softmax) ----------------
// 128-row q-tile per block; no running max / no rescaling: p = exp2(s_masked),
// row-sum via ones-column MFMA, divide at epilogue. Iterations have no serial
// softmax dependency -> deep pipelining across waves.
// grid: (T/128=16, B=4, HEADS=7), block 256. LDS 45 KB -> 3 blocks/CU.
__global__ __launch_bounds__(256, 3) void fano_attn(
    const short* __restrict__ Q, const short* __restrict__ K, const short* __restrict__ Vt,
    short* __restrict__ Ocat, const int* __restrict__ iscp)
{
    __shared__ short Ks[64 * 136];
    __shared__ short Vs[128 * 72];
    __shared__ short Ps[4][16 * 72];

    const int causal = *iscp;
    const int qt = causal ? ((int)gridDim.x - 1 - blockIdx.x) : blockIdx.x;
    const int q0 = qt * 128;
    const int b = blockIdx.y, h = blockIdx.z;
    const int tid = threadIdx.x, wave = tid >> 6, lane = tid & 63;
    const int quad = lane >> 4, l16 = lane & 15;
    const int iw = q0 + wave * 32;   // wave's min q-row

    const short* Qb = Q + (size_t)(h * MTOT + b * TT + q0) * HDIM;
    const short* Kb = K + (size_t)(h * MTOT + b * TT) * HDIM;
    const short* Vb = Vt + (size_t)h * MTOT * HDIM + (size_t)b * HDIM * TT;

    // Q fragments direct from global (scale*log2e folded at projection)
    bf16x8 qf[2][4];
    for (int g = 0; g < 2; g++)
        for (int ks = 0; ks < 4; ks++)
            qf[g][ks] = *(const bf16x8*)(Qb + (size_t)(wave * 32 + g * 16 + l16) * HDIM + ks * 32 + quad * 8);

    f32x4 oacc[2][8] = {};
    f32x4 lacc[2] = {};
    int irow[2][4];
    for (int g = 0; g < 2; g++)
        for (int r = 0; r < 4; r++)
            irow[g][r] = q0 + wave * 32 + g * 16 + quad * 4 + r;

    const bf16x8 vones = {0x3F80, 0x3F80, 0x3F80, 0x3F80, 0x3F80, 0x3F80, 0x3F80, 0x3F80};

    // staging maps (16B chunks, 4 per thread per tile)
    int krow[4], kcol[4], vrow[4], vcol[4];
    for (int i = 0; i < 4; i++) {
        int c = tid + i * 256;
        krow[i] = c >> 4; kcol[i] = (c & 15) * 8;
        vrow[i] = c >> 3; vcol[i] = (c & 7) * 8;
    }

    const int send = causal ? (q0 + 128) : TT;

    bf16x8 kreg[4], vreg[4];
    for (int i = 0; i < 4; i++) {
        kreg[i] = *(const bf16x8*)(Kb + (size_t)krow[i] * HDIM + kcol[i]);
        vreg[i] = *(const bf16x8*)(Vb + (size_t)vrow[i] * TT + vcol[i]);
    }

    int d7b = (l16 - h + 7) % 7;   // (s - h) mod 7 at s = s0 + l16
    short* Pw = &Ps[wave][0];

    for (int s0 = 0; s0 < send; s0 += 64) {
        __syncthreads();
        for (int i = 0; i < 4; i++) {
            *(bf16x8*)(Ks + krow[i] * 136 + kcol[i]) = kreg[i];
            *(bf16x8*)(Vs + vrow[i] * 72 + vcol[i]) = vreg[i];
        }
        __syncthreads();

        int sn = s0 + 64; if (sn >= send) sn = s0;
        const short* Kn = Kb + (size_t)sn * HDIM;
        const short* Vn = Vb + sn;
        for (int i = 0; i < 4; i++) {
            kreg[i] = *(const bf16x8*)(Kn + (size_t)krow[i] * HDIM + kcol[i]);
            vreg[i] = *(const bf16x8*)(Vn + (size_t)vrow[i] * TT + vcol[i]);
        }

        // S = Q K^T (log2 domain)
        f32x4 sacc[2][4] = {};
        for (int ni = 0; ni < 4; ni++)
            for (int ks = 0; ks < 4; ks++) {
                bf16x8 bk = *(const bf16x8*)(Ks + (ni * 16 + l16) * 136 + ks * 32 + quad * 8);
                sacc[0][ni] = __builtin_amdgcn_mfma_f32_16x16x32_bf16(qf[0][ks], bk, sacc[0][ni], 0, 0, 0);
                sacc[1][ni] = __builtin_amdgcn_mfma_f32_16x16x32_bf16(qf[1][ks], bk, sacc[1][ni], 0, 0, 0);
            }

        // mask + exp2 (static base: no max tracking, no rescale)
        const bool full = (s0 + 80 > iw) && (causal || (s0 < iw + 48));
        if (full) {
            for (int ni = 0; ni < 4; ni++) {
                int d7 = d7b + 2 * ni; if (d7 >= 7) d7 -= 7;
                bool line = (0x0B >> d7) & 1;
                int s = s0 + ni * 16 + l16;
                for (int g = 0; g < 2; g++)
                    for (int r = 0; r < 4; r++) {
                        int i = irow[g][r];
                        bool ok = causal ? ((s <= i) & (line | (s >= i - 16)))
                                         : (line | ((s >= i - 16) & (s <= i + 16)));
                        sacc[g][ni][r] = exp2f(ok ? sacc[g][ni][r] : -1e30f);
                    }
            }
        } else {
            for (int ni = 0; ni < 4; ni++) {
                int d7 = d7b + 2 * ni; if (d7 >= 7) d7 -= 7;
                bool line = (0x0B >> d7) & 1;
                for (int g = 0; g < 2; g++)
                    for (int r = 0; r < 4; r++)
                        sacc[g][ni][r] = exp2f(line ? sacc[g][ni][r] : -1e30f);
            }
        }
        d7b++; if (d7b == 7) d7b = 0;

        // per row-group: P -> wave-private LDS -> A-frags; PV + ones-column rowsum
        for (int g = 0; g < 2; g++) {
            for (int ni = 0; ni < 4; ni++)
                for (int r = 0; r < 4; r++)
                    Pw[(quad * 4 + r) * 72 + ni * 16 + l16] = f2bf(sacc[g][ni][r]);
            for (int ks2 = 0; ks2 < 2; ks2++) {
                bf16x8 ap = *(const bf16x8*)(Pw + l16 * 72 + ks2 * 32 + quad * 8);
                lacc[g] = __builtin_amdgcn_mfma_f32_16x16x32_bf16(ap, vones, lacc[g], 0, 0, 0);
                for (int nj = 0; nj < 8; nj++) {
                    bf16x8 bv = *(const bf16x8*)(Vs + (nj * 16 + l16) * 72 + ks2 * 32 + quad * 8);
                    oacc[g][nj] = __builtin_amdgcn_mfma_f32_16x16x32_bf16(ap, bv, oacc[g][nj], 0, 0, 0);
                }
            }
        }
    }

    short* Obase = Ocat + (size_t)(b * TT) * HIDDEN + h * HDIM;
    for (int g = 0; g < 2; g++) {
        float inv[4];
        for (int r = 0; r < 4; r++) inv[r] = 1.0f / lacc[g][r];
        for (int nj = 0; nj < 8; nj++)
            for (int r = 0; r < 4; r++)
                Obase[(size_t)irow[g][r] * HIDDEN + nj * 16 + l16] = f2bf(oacc[g][nj][r] * inv[r]);
    }
}

// ---------------- kernel 4: output projection (128x128 tile) ----------------
__global__ __launch_bounds__(256) void out_gemm(
    const short* __restrict__ A, const short* __restrict__ Bt, float* __restrict__ out)
{
    __shared__ short Ash[128 * 40];
    __shared__ short Bsh[128 * 40];
    const int m0 = blockIdx.x * 128;
    const int n0 = blockIdx.y * 128;

    const int tid = threadIdx.x;
    const int wave = tid >> 6, lane = tid & 63;
    const int quad = lane >> 4, l16 = lane & 15;
    const int wm = (wave >> 1) * 64, wn = (wave & 1) * 64;

    f32x4 acc[4][4] = {};
    const int sr = tid >> 2, sc = (tid & 3) * 8;

    for (int k0 = 0; k0 < HIDDEN; k0 += 32) {
        bf16x8 a0 = *(const bf16x8*)(A + (size_t)(m0 + sr) * HIDDEN + k0 + sc);
        bf16x8 a1 = *(const bf16x8*)(A + (size_t)(m0 + sr + 64) * HIDDEN + k0 + sc);
        bf16x8 b0 = *(const bf16x8*)(Bt + (size_t)(n0 + sr) * HIDDEN + k0 + sc);
        bf16x8 b1 = *(const bf16x8*)(Bt + (size_t)(n0 + sr + 64) * HIDDEN + k0 + sc);
        __syncthreads();
        *(bf16x8*)(Ash + sr * 40 + sc) = a0;
        *(bf16x8*)(Ash + (sr + 64) * 40 + sc) = a1;
        *(bf16x8*)(Bsh + sr * 40 + sc) = b0;
        *(bf16x8*)(Bsh + (sr + 64) * 40 + sc) = b1;
        __syncthreads();
        bf16x8 af[4], bfr[4];
        for (int mi = 0; mi < 4; mi++)
            af[mi] = *(const bf16x8*)(Ash + (wm + mi * 16 + l16) * 40 + quad * 8);
        for (int ni = 0; ni < 4; ni++)
            bfr[ni] = *(const bf16x8*)(Bsh + (wn + ni * 16 + l16) * 40 + quad * 8);
        for (int mi = 0; mi < 4; mi++)
            for (int ni = 0; ni < 4; ni++)
                acc[mi][ni] = __builtin_amdgcn_mfma_f32_16x16x32_bf16(af[mi], bfr[ni], acc[mi][ni], 0, 0, 0);
    }

    for (int mi = 0; mi < 4; mi++)
        for (int ni = 0; ni < 4; ni++)
            for (int r = 0; r < 4; r++) {
                int m = m0 + wm + mi * 16 + quad * 4 + r;
                int n = n0 + wn + ni * 16 + l16;
                out[(size_t)m * HIDDEN + n] = acc[mi][ni][r];
            }
}

extern "C" void kernel_launch(void* const* d_in, const int* in_sizes, int n_in,
                              void* d_out, int out_size, void* d_ws, size_t ws_size,
                              hipStream_t stream) {
    (void)in_sizes; (void)n_in; (void)out_size; (void)ws_size;
    const float* x  = (const float*)d_in[0];
    const float* Wq = (const float*)d_in[1];
    const float* Wk = (const float*)d_in[2];
    const float* Wv = (const float*)d_in[3];
    const float* Wo = (const float*)d_in[4];
    const int* iscp = (const int*)d_in[5];
    float* out = (float*)d_out;

    short* xb   = (short*)d_ws;                       // 8192*896
    short* Qb   = xb   + (size_t)MTOT * HIDDEN;       // 7*8192*128 each
    short* Kb   = Qb   + (size_t)HEADS * MTOT * HDIM;
    short* Vtb  = Kb   + (size_t)HEADS * MTOT * HDIM;
    short* Ocat = Vtb  + (size_t)HEADS * MTOT * HDIM; // 8192*896 (aliased with Wt)
    short* Wt   = Ocat;                               // 21*128*896, used only before attn
    short* Wob  = Ocat + (size_t)MTOT * HIDDEN;       // 896*896

    cast_x_kernel<<<(MTOT * HIDDEN) / (256 * 4), 256, 0, stream>>>(x, xb);
    cast_wo_kernel<<<(HIDDEN * HIDDEN) / (256 * 4), 256, 0, stream>>>(Wo, Wob);
    transpose_cast_w<<<dim3(HIDDEN / 32, HDIM / 32, 21), 256, 0, stream>>>(Wq, Wk, Wv, Wt);
    qkv_gemm<<<dim3(MTOT / 128, 21), 256, 0, stream>>>(xb, Wt, Qb, Kb, Vtb);
    fano_attn<<<dim3(TT / 128, BB, HEADS), 256, 0, stream>>>(Qb, Kb, Vtb, Ocat, iscp);
    out_gemm<<<dim3(MTOT / 128, HIDDEN / 128), 256, 0, stream>>>(Ocat, Wob, out);
}

// Round 7
// 372.218 us; speedup vs baseline: 1.5042x; 1.5042x over previous
//
#include <hip/hip_runtime.h>
#include <hip/hip_bf16.h>

#define HIDDEN 896
#define HEADS 7
#define HDIM 128
#define BB 4
#define TT 2048
#define MTOT (BB*TT)   // 8192

typedef short bf16x8 __attribute__((ext_vector_type(8)));
typedef float f32x4 __attribute__((ext_vector_type(4)));

__device__ __forceinline__ short f2bf(float f) {
    union { float f; unsigned u; } v; v.f = f;
    unsigned r = (v.u + 0x7FFF + ((v.u >> 16) & 1)) >> 16;
    return (short)r;
}

// ---------------- kernel 1: cast x (fp32) -> bf16 ----------------
__global__ __launch_bounds__(256) void cast_x_kernel(const float* __restrict__ x,
                                                     short* __restrict__ xb) {
    int base = (blockIdx.x * 256 + threadIdx.x) * 4;
    if (base < MTOT * HIDDEN) {
        float4 v = *(const float4*)(x + base);
        short4 o;
        o.x = f2bf(v.x); o.y = f2bf(v.y); o.z = f2bf(v.z); o.w = f2bf(v.w);
        *(short4*)(xb + base) = o;
    }
}

// cast Wo fp32[896][896] -> bf16 (already B^T form [n][k])
__global__ __launch_bounds__(256) void cast_wo_kernel(const float* __restrict__ src,
                                                      short* __restrict__ dst) {
    int base = (blockIdx.x * 256 + threadIdx.x) * 4;
    if (base < HIDDEN * HIDDEN) {
        float4 v = *(const float4*)(src + base);
        short4 o;
        o.x = f2bf(v.x); o.y = f2bf(v.y); o.z = f2bf(v.z); o.w = f2bf(v.w);
        *(short4*)(dst + base) = o;
    }
}

// transpose-cast Wq/Wk/Wv fp32 [head][896 k][128 n] -> bf16 Wt[type*7+head][128 n][896 k]
__global__ __launch_bounds__(256) void transpose_cast_w(
    const float* __restrict__ Wq, const float* __restrict__ Wk,
    const float* __restrict__ Wv, short* __restrict__ Wt)
{
    __shared__ float tile[32][33];
    const int z = blockIdx.z;
    const int type = z / 7, head = z % 7;
    const float* src = (type == 0 ? Wq : (type == 1 ? Wk : Wv)) + head * (HIDDEN * HDIM);
    short* dst = Wt + (size_t)z * (HDIM * HIDDEN);
    const int r0 = blockIdx.x * 32, c0 = blockIdx.y * 32;
    const int tx = threadIdx.x & 31, ty = threadIdx.x >> 5;  // 32 x 8
    for (int i = 0; i < 4; i++)
        tile[ty * 4 + i][tx] = src[(r0 + ty * 4 + i) * HDIM + c0 + tx];
    __syncthreads();
    for (int i = 0; i < 4; i++)
        dst[(c0 + ty * 4 + i) * HIDDEN + r0 + tx] = f2bf(tile[tx][ty * 4 + i]);
}

// ---------------- kernel 2: QKV projection GEMM (128x128 tile) ----------------
__global__ __launch_bounds__(256) void qkv_gemm(
    const short* __restrict__ xb, const short* __restrict__ Wt,
    short* __restrict__ Q, short* __restrict__ Kk, short* __restrict__ Vt)
{
    __shared__ short Ash[128 * 40];
    __shared__ short Bsh[128 * 40];
    const int m0 = blockIdx.x * 128;
    const int z = blockIdx.y;
    const int head = z % 7, type = z / 7;
    const short* Wz = Wt + (size_t)z * (HDIM * HIDDEN);

    const int tid = threadIdx.x;
    const int wave = tid >> 6, lane = tid & 63;
    const int quad = lane >> 4, l16 = lane & 15;
    const int wm = (wave >> 1) * 64, wn = (wave & 1) * 64;

    f32x4 acc[4][4] = {};
    const int sr = tid >> 2, sc = (tid & 3) * 8;

    for (int k0 = 0; k0 < HIDDEN; k0 += 32) {
        bf16x8 a0 = *(const bf16x8*)(xb + (size_t)(m0 + sr) * HIDDEN + k0 + sc);
        bf16x8 a1 = *(const bf16x8*)(xb + (size_t)(m0 + sr + 64) * HIDDEN + k0 + sc);
        bf16x8 b0 = *(const bf16x8*)(Wz + (size_t)sr * HIDDEN + k0 + sc);
        bf16x8 b1 = *(const bf16x8*)(Wz + (size_t)(sr + 64) * HIDDEN + k0 + sc);
        __syncthreads();
        *(bf16x8*)(Ash + sr * 40 + sc) = a0;
        *(bf16x8*)(Ash + (sr + 64) * 40 + sc) = a1;
        *(bf16x8*)(Bsh + sr * 40 + sc) = b0;
        *(bf16x8*)(Bsh + (sr + 64) * 40 + sc) = b1;
        __syncthreads();
        bf16x8 af[4], bfr[4];
        for (int mi = 0; mi < 4; mi++)
            af[mi] = *(const bf16x8*)(Ash + (wm + mi * 16 + l16) * 40 + quad * 8);
        for (int ni = 0; ni < 4; ni++)
            bfr[ni] = *(const bf16x8*)(Bsh + (wn + ni * 16 + l16) * 40 + quad * 8);
        for (int mi = 0; mi < 4; mi++)
            for (int ni = 0; ni < 4; ni++)
                acc[mi][ni] = __builtin_amdgcn_mfma_f32_16x16x32_bf16(af[mi], bfr[ni], acc[mi][ni], 0, 0, 0);
    }

    const size_t base = (size_t)head * (MTOT * HDIM);
    if (type == 0) {
        // fold softmax scale AND log2(e) into Q (softmax done in exp2 domain)
        const float qs = 0.08838834764831845f * 1.4426950408889634f;
        for (int mi = 0; mi < 4; mi++)
            for (int ni = 0; ni < 4; ni++)
                for (int r = 0; r < 4; r++) {
                    int m = m0 + wm + mi * 16 + quad * 4 + r;
                    int n = wn + ni * 16 + l16;
                    Q[base + (size_t)m * HDIM + n] = f2bf(acc[mi][ni][r] * qs);
                }
    } else if (type == 1) {
        for (int mi = 0; mi < 4; mi++)
            for (int ni = 0; ni < 4; ni++)
                for (int r = 0; r < 4; r++) {
                    int m = m0 + wm + mi * 16 + quad * 4 + r;
                    int n = wn + ni * 16 + l16;
                    Kk[base + (size_t)m * HDIM + n] = f2bf(acc[mi][ni][r]);
                }
    } else {
        for (int mi = 0; mi < 4; mi++)
            for (int ni = 0; ni < 4; ni++) {
                int m = m0 + wm + mi * 16 + quad * 4;
                int bb = m >> 11, t = m & 2047;
                int n = wn + ni * 16 + l16;
                short4 o;
                o.x = f2bf(acc[mi][ni][0]); o.y = f2bf(acc[mi][ni][1]);
                o.z = f2bf(acc[mi][ni][2]); o.w = f2bf(acc[mi][ni][3]);
                *(short4*)(Vt + base + (size_t)bb * (HDIM * TT) + (size_t)n * TT + t) = o;
            }
    }
}

// ---------------- kernel 3: fano flash attention v7 ----------------
// Static-base softmax (no running max / rescale), 128-row q-tile,
// NO register cap (r4-r6's (256,3) bound caused catastrophic scratch spills),
// full 32-row per-wave P buffer. LDS 54.3 KB -> 2 blocks/CU.
// grid: (T/128=16, B=4, HEADS=7), block 256.
__global__ __launch_bounds__(256) void fano_attn(
    const short* __restrict__ Q, const short* __restrict__ K, const short* __restrict__ Vt,
    short* __restrict__ Ocat, const int* __restrict__ iscp)
{
    __shared__ short Ks[64 * 136];
    __shared__ short Vs[128 * 72];
    __shared__ short Ps[4][32 * 72];

    const int causal = *iscp;
    const int qt = causal ? ((int)gridDim.x - 1 - blockIdx.x) : blockIdx.x;
    const int q0 = qt * 128;
    const int b = blockIdx.y, h = blockIdx.z;
    const int tid = threadIdx.x, wave = tid >> 6, lane = tid & 63;
    const int quad = lane >> 4, l16 = lane & 15;
    const int iw = q0 + wave * 32;   // wave's min q-row

    const short* Qb = Q + (size_t)(h * MTOT + b * TT + q0) * HDIM;
    const short* Kb = K + (size_t)(h * MTOT + b * TT) * HDIM;
    const short* Vb = Vt + (size_t)h * MTOT * HDIM + (size_t)b * HDIM * TT;

    // Q fragments direct from global (scale*log2e folded at projection)
    bf16x8 qf[2][4];
    for (int g = 0; g < 2; g++)
        for (int ks = 0; ks < 4; ks++)
            qf[g][ks] = *(const bf16x8*)(Qb + (size_t)(wave * 32 + g * 16 + l16) * HDIM + ks * 32 + quad * 8);

    f32x4 oacc[2][8] = {};
    f32x4 lacc[2] = {};
    int irow[2][4];
    for (int g = 0; g < 2; g++)
        for (int r = 0; r < 4; r++)
            irow[g][r] = q0 + wave * 32 + g * 16 + quad * 4 + r;

    const bf16x8 vones = {0x3F80, 0x3F80, 0x3F80, 0x3F80, 0x3F80, 0x3F80, 0x3F80, 0x3F80};

    // staging maps (16B chunks, 4 per thread per tile)
    int krow[4], kcol[4], vrow[4], vcol[4];
    for (int i = 0; i < 4; i++) {
        int c = tid + i * 256;
        krow[i] = c >> 4; kcol[i] = (c & 15) * 8;
        vrow[i] = c >> 3; vcol[i] = (c & 7) * 8;
    }

    const int send = causal ? (q0 + 128) : TT;

    bf16x8 kreg[4], vreg[4];
    for (int i = 0; i < 4; i++) {
        kreg[i] = *(const bf16x8*)(Kb + (size_t)krow[i] * HDIM + kcol[i]);
        vreg[i] = *(const bf16x8*)(Vb + (size_t)vrow[i] * TT + vcol[i]);
    }

    int d7b = (l16 - h + 7) % 7;   // (s - h) mod 7 at s = s0 + l16
    short* Pw = &Ps[wave][0];

    for (int s0 = 0; s0 < send; s0 += 64) {
        __syncthreads();
        for (int i = 0; i < 4; i++) {
            *(bf16x8*)(Ks + krow[i] * 136 + kcol[i]) = kreg[i];
            *(bf16x8*)(Vs + vrow[i] * 72 + vcol[i]) = vreg[i];
        }
        __syncthreads();

        int sn = s0 + 64; if (sn >= send) sn = s0;
        const short* Kn = Kb + (size_t)sn * HDIM;
        const short* Vn = Vb + sn;
        for (int i = 0; i < 4; i++) {
            kreg[i] = *(const bf16x8*)(Kn + (size_t)krow[i] * HDIM + kcol[i]);
            vreg[i] = *(const bf16x8*)(Vn + (size_t)vrow[i] * TT + vcol[i]);
        }

        // S = Q K^T (log2 domain)
        f32x4 sacc[2][4] = {};
        for (int ni = 0; ni < 4; ni++)
            for (int ks = 0; ks < 4; ks++) {
                bf16x8 bk = *(const bf16x8*)(Ks + (ni * 16 + l16) * 136 + ks * 32 + quad * 8);
                sacc[0][ni] = __builtin_amdgcn_mfma_f32_16x16x32_bf16(qf[0][ks], bk, sacc[0][ni], 0, 0, 0);
                sacc[1][ni] = __builtin_amdgcn_mfma_f32_16x16x32_bf16(qf[1][ks], bk, sacc[1][ni], 0, 0, 0);
            }

        // mask + exp2 (static base: no max tracking, no rescale)
        const bool full = (s0 + 80 > iw) && (causal || (s0 < iw + 48));
        if (full) {
            for (int ni = 0; ni < 4; ni++) {
                int d7 = d7b + 2 * ni; if (d7 >= 7) d7 -= 7;
                bool line = (0x0B >> d7) & 1;
                int s = s0 + ni * 16 + l16;
                for (int g = 0; g < 2; g++)
                    for (int r = 0; r < 4; r++) {
                        int i = irow[g][r];
                        bool ok = causal ? ((s <= i) & (line | (s >= i - 16)))
                                         : (line | ((s >= i - 16) & (s <= i + 16)));
                        sacc[g][ni][r] = ok ? exp2f(sacc[g][ni][r]) : 0.0f;
                    }
            }
        } else {
            for (int ni = 0; ni < 4; ni++) {
                int d7 = d7b + 2 * ni; if (d7 >= 7) d7 -= 7;
                bool line = (0x0B >> d7) & 1;
                for (int g = 0; g < 2; g++)
                    for (int r = 0; r < 4; r++)
                        sacc[g][ni][r] = line ? exp2f(sacc[g][ni][r]) : 0.0f;
            }
        }
        d7b++; if (d7b == 7) d7b = 0;

        // P: C-layout regs -> wave-private LDS (both groups) -> A-layout frags
        for (int g = 0; g < 2; g++)
            for (int ni = 0; ni < 4; ni++)
                for (int r = 0; r < 4; r++)
                    Pw[(g * 16 + quad * 4 + r) * 72 + ni * 16 + l16] = f2bf(sacc[g][ni][r]);

        // O += P V ; row-sums via ones-column MFMA
        for (int ks2 = 0; ks2 < 2; ks2++) {
            bf16x8 ap0 = *(const bf16x8*)(Pw + l16 * 72 + ks2 * 32 + quad * 8);
            bf16x8 ap1 = *(const bf16x8*)(Pw + (16 + l16) * 72 + ks2 * 32 + quad * 8);
            lacc[0] = __builtin_amdgcn_mfma_f32_16x16x32_bf16(ap0, vones, lacc[0], 0, 0, 0);
            lacc[1] = __builtin_amdgcn_mfma_f32_16x16x32_bf16(ap1, vones, lacc[1], 0, 0, 0);
            for (int nj = 0; nj < 8; nj++) {
                bf16x8 bv = *(const bf16x8*)(Vs + (nj * 16 + l16) * 72 + ks2 * 32 + quad * 8);
                oacc[0][nj] = __builtin_amdgcn_mfma_f32_16x16x32_bf16(ap0, bv, oacc[0][nj], 0, 0, 0);
                oacc[1][nj] = __builtin_amdgcn_mfma_f32_16x16x32_bf16(ap1, bv, oacc[1][nj], 0, 0, 0);
            }
        }
    }

    short* Obase = Ocat + (size_t)(b * TT) * HIDDEN + h * HDIM;
    for (int g = 0; g < 2; g++) {
        float inv[4];
        for (int r = 0; r < 4; r++) inv[r] = 1.0f / lacc[g][r];
        for (int nj = 0; nj < 8; nj++)
            for (int r = 0; r < 4; r++)
                Obase[(size_t)irow[g][r] * HIDDEN + nj * 16 + l16] = f2bf(oacc[g][nj][r] * inv[r]);
    }
}

// ---------------- kernel 4: output projection (128x128 tile) ----------------
__global__ __launch_bounds__(256) void out_gemm(
    const short* __restrict__ A, const short* __restrict__ Bt, float* __restrict__ out)
{
    __shared__ short Ash[128 * 40];
    __shared__ short Bsh[128 * 40];
    const int m0 = blockIdx.x * 128;
    const int n0 = blockIdx.y * 128;

    const int tid = threadIdx.x;
    const int wave = tid >> 6, lane = tid & 63;
    const int quad = lane >> 4, l16 = lane & 15;
    const int wm = (wave >> 1) * 64, wn = (wave & 1) * 64;

    f32x4 acc[4][4] = {};
    const int sr = tid >> 2, sc = (tid & 3) * 8;

    for (int k0 = 0; k0 < HIDDEN; k0 += 32) {
        bf16x8 a0 = *(const bf16x8*)(A + (size_t)(m0 + sr) * HIDDEN + k0 + sc);
        bf16x8 a1 = *(const bf16x8*)(A + (size_t)(m0 + sr + 64) * HIDDEN + k0 + sc);
        bf16x8 b0 = *(const bf16x8*)(Bt + (size_t)(n0 + sr) * HIDDEN + k0 + sc);
        bf16x8 b1 = *(const bf16x8*)(Bt + (size_t)(n0 + sr + 64) * HIDDEN + k0 + sc);
        __syncthreads();
        *(bf16x8*)(Ash + sr * 40 + sc) = a0;
        *(bf16x8*)(Ash + (sr + 64) * 40 + sc) = a1;
        *(bf16x8*)(Bsh + sr * 40 + sc) = b0;
        *(bf16x8*)(Bsh + (sr + 64) * 40 + sc) = b1;
        __syncthreads();
        bf16x8 af[4], bfr[4];
        for (int mi = 0; mi < 4; mi++)
            af[mi] = *(const bf16x8*)(Ash + (wm + mi * 16 + l16) * 40 + quad * 8);
        for (int ni = 0; ni < 4; ni++)
            bfr[ni] = *(const bf16x8*)(Bsh + (wn + ni * 16 + l16) * 40 + quad * 8);
        for (int mi = 0; mi < 4; mi++)
            for (int ni = 0; ni < 4; ni++)
                acc[mi][ni] = __builtin_amdgcn_mfma_f32_16x16x32_bf16(af[mi], bfr[ni], acc[mi][ni], 0, 0, 0);
    }

    for (int mi = 0; mi < 4; mi++)
        for (int ni = 0; ni < 4; ni++)
            for (int r = 0; r < 4; r++) {
                int m = m0 + wm + mi * 16 + quad * 4 + r;
                int n = n0 + wn + ni * 16 + l16;
                out[(size_t)m * HIDDEN + n] = acc[mi][ni][r];
            }
}

extern "C" void kernel_launch(void* const* d_in, const int* in_sizes, int n_in,
                              void* d_out, int out_size, void* d_ws, size_t ws_size,
                              hipStream_t stream) {
    (void)in_sizes; (void)n_in; (void)out_size; (void)ws_size;
    const float* x  = (const float*)d_in[0];
    const float* Wq = (const float*)d_in[1];
    const float* Wk = (const float*)d_in[2];
    const float* Wv = (const float*)d_in[3];
    const float* Wo = (const float*)d_in[4];
    const int* iscp = (const int*)d_in[5];
    float* out = (float*)d_out;

    short* xb   = (short*)d_ws;                       // 8192*896
    short* Qb   = xb   + (size_t)MTOT * HIDDEN;       // 7*8192*128 each
    short* Kb   = Qb   + (size_t)HEADS * MTOT * HDIM;
    short* Vtb  = Kb   + (size_t)HEADS * MTOT * HDIM;
    short* Ocat = Vtb  + (size_t)HEADS * MTOT * HDIM; // 8192*896 (aliased with Wt)
    short* Wt   = Ocat;                               // 21*128*896, used only before attn
    short* Wob  = Ocat + (size_t)MTOT * HIDDEN;       // 896*896

    cast_x_kernel<<<(MTOT * HIDDEN) / (256 * 4), 256, 0, stream>>>(x, xb);
    cast_wo_kernel<<<(HIDDEN * HIDDEN) / (256 * 4), 256, 0, stream>>>(Wo, Wob);
    transpose_cast_w<<<dim3(HIDDEN / 32, HDIM / 32, 21), 256, 0, stream>>>(Wq, Wk, Wv, Wt);
    qkv_gemm<<<dim3(MTOT / 128, 21), 256, 0, stream>>>(xb, Wt, Qb, Kb, Vtb);
    fano_attn<<<dim3(TT / 128, BB, HEADS), 256, 0, stream>>>(Qb, Kb, Vtb, Ocat, iscp);
    out_gemm<<<dim3(MTOT / 128, HIDDEN / 128), 256, 0, stream>>>(Ocat, Wob, out);
}

// Round 8
// 344.400 us; speedup vs baseline: 1.6257x; 1.0808x over previous
//
#include <hip/hip_runtime.h>
#include <hip/hip_bf16.h>

#define HIDDEN 896
#define HEADS 7
#define HDIM 128
#define BB 4
#define TT 2048
#define MTOT (BB*TT)   // 8192

typedef short bf16x8 __attribute__((ext_vector_type(8)));
typedef float f32x4 __attribute__((ext_vector_type(4)));

__device__ __forceinline__ short f2bf(float f) {
    union { float f; unsigned u; } v; v.f = f;
    unsigned r = (v.u + 0x7FFF + ((v.u >> 16) & 1)) >> 16;
    return (short)r;
}

// ---------------- kernel 1: cast x (fp32) -> bf16 ----------------
__global__ __launch_bounds__(256) void cast_x_kernel(const float* __restrict__ x,
                                                     short* __restrict__ xb) {
    int base = (blockIdx.x * 256 + threadIdx.x) * 4;
    if (base < MTOT * HIDDEN) {
        float4 v = *(const float4*)(x + base);
        short4 o;
        o.x = f2bf(v.x); o.y = f2bf(v.y); o.z = f2bf(v.z); o.w = f2bf(v.w);
        *(short4*)(xb + base) = o;
    }
}

// cast Wo fp32[896][896] -> bf16 (already B^T form [n][k])
__global__ __launch_bounds__(256) void cast_wo_kernel(const float* __restrict__ src,
                                                      short* __restrict__ dst) {
    int base = (blockIdx.x * 256 + threadIdx.x) * 4;
    if (base < HIDDEN * HIDDEN) {
        float4 v = *(const float4*)(src + base);
        short4 o;
        o.x = f2bf(v.x); o.y = f2bf(v.y); o.z = f2bf(v.z); o.w = f2bf(v.w);
        *(short4*)(dst + base) = o;
    }
}

// transpose-cast Wq/Wk/Wv fp32 [head][896 k][128 n] -> bf16 Wt[type*7+head][128 n][896 k]
__global__ __launch_bounds__(256) void transpose_cast_w(
    const float* __restrict__ Wq, const float* __restrict__ Wk,
    const float* __restrict__ Wv, short* __restrict__ Wt)
{
    __shared__ float tile[32][33];
    const int z = blockIdx.z;
    const int type = z / 7, head = z % 7;
    const float* src = (type == 0 ? Wq : (type == 1 ? Wk : Wv)) + head * (HIDDEN * HDIM);
    short* dst = Wt + (size_t)z * (HDIM * HIDDEN);
    const int r0 = blockIdx.x * 32, c0 = blockIdx.y * 32;
    const int tx = threadIdx.x & 31, ty = threadIdx.x >> 5;  // 32 x 8
    for (int i = 0; i < 4; i++)
        tile[ty * 4 + i][tx] = src[(r0 + ty * 4 + i) * HDIM + c0 + tx];
    __syncthreads();
    for (int i = 0; i < 4; i++)
        dst[(c0 + ty * 4 + i) * HIDDEN + r0 + tx] = f2bf(tile[tx][ty * 4 + i]);
}

// ---------------- kernel 2: QKV projection GEMM (128x128 tile) ----------------
__global__ __launch_bounds__(256) void qkv_gemm(
    const short* __restrict__ xb, const short* __restrict__ Wt,
    short* __restrict__ Q, short* __restrict__ Kk, short* __restrict__ Vt)
{
    __shared__ short Ash[128 * 40];
    __shared__ short Bsh[128 * 40];
    const int m0 = blockIdx.x * 128;
    const int z = blockIdx.y;
    const int head = z % 7, type = z / 7;
    const short* Wz = Wt + (size_t)z * (HDIM * HIDDEN);

    const int tid = threadIdx.x;
    const int wave = tid >> 6, lane = tid & 63;
    const int quad = lane >> 4, l16 = lane & 15;
    const int wm = (wave >> 1) * 64, wn = (wave & 1) * 64;

    f32x4 acc[4][4] = {};
    const int sr = tid >> 2, sc = (tid & 3) * 8;

    for (int k0 = 0; k0 < HIDDEN; k0 += 32) {
        bf16x8 a0 = *(const bf16x8*)(xb + (size_t)(m0 + sr) * HIDDEN + k0 + sc);
        bf16x8 a1 = *(const bf16x8*)(xb + (size_t)(m0 + sr + 64) * HIDDEN + k0 + sc);
        bf16x8 b0 = *(const bf16x8*)(Wz + (size_t)sr * HIDDEN + k0 + sc);
        bf16x8 b1 = *(const bf16x8*)(Wz + (size_t)(sr + 64) * HIDDEN + k0 + sc);
        __syncthreads();
        *(bf16x8*)(Ash + sr * 40 + sc) = a0;
        *(bf16x8*)(Ash + (sr + 64) * 40 + sc) = a1;
        *(bf16x8*)(Bsh + sr * 40 + sc) = b0;
        *(bf16x8*)(Bsh + (sr + 64) * 40 + sc) = b1;
        __syncthreads();
        bf16x8 af[4], bfr[4];
        for (int mi = 0; mi < 4; mi++)
            af[mi] = *(const bf16x8*)(Ash + (wm + mi * 16 + l16) * 40 + quad * 8);
        for (int ni = 0; ni < 4; ni++)
            bfr[ni] = *(const bf16x8*)(Bsh + (wn + ni * 16 + l16) * 40 + quad * 8);
        for (int mi = 0; mi < 4; mi++)
            for (int ni = 0; ni < 4; ni++)
                acc[mi][ni] = __builtin_amdgcn_mfma_f32_16x16x32_bf16(af[mi], bfr[ni], acc[mi][ni], 0, 0, 0);
    }

    const size_t base = (size_t)head * (MTOT * HDIM);
    if (type == 0) {
        // fold softmax scale AND log2(e) into Q (softmax done in exp2 domain)
        const float qs = 0.08838834764831845f * 1.4426950408889634f;
        for (int mi = 0; mi < 4; mi++)
            for (int ni = 0; ni < 4; ni++)
                for (int r = 0; r < 4; r++) {
                    int m = m0 + wm + mi * 16 + quad * 4 + r;
                    int n = wn + ni * 16 + l16;
                    Q[base + (size_t)m * HDIM + n] = f2bf(acc[mi][ni][r] * qs);
                }
    } else if (type == 1) {
        for (int mi = 0; mi < 4; mi++)
            for (int ni = 0; ni < 4; ni++)
                for (int r = 0; r < 4; r++) {
                    int m = m0 + wm + mi * 16 + quad * 4 + r;
                    int n = wn + ni * 16 + l16;
                    Kk[base + (size_t)m * HDIM + n] = f2bf(acc[mi][ni][r]);
                }
    } else {
        for (int mi = 0; mi < 4; mi++)
            for (int ni = 0; ni < 4; ni++) {
                int m = m0 + wm + mi * 16 + quad * 4;
                int bb = m >> 11, t = m & 2047;
                int n = wn + ni * 16 + l16;
                short4 o;
                o.x = f2bf(acc[mi][ni][0]); o.y = f2bf(acc[mi][ni][1]);
                o.z = f2bf(acc[mi][ni][2]); o.w = f2bf(acc[mi][ni][3]);
                *(short4*)(Vt + base + (size_t)bb * (HDIM * TT) + (size_t)n * TT + t) = o;
            }
    }
}

// ---------------- kernel 3: fano flash attention v8 ----------------
// Identical compute to v7 (static-base softmax, 128-row q-tile, no reg cap).
// ONLY change: load-balanced q-tile schedule. Block linear id p = x + 16*(b+4h);
// under round-robin placement blocks p and p+256 share a CU. v7 set qt=15-x for
// ALL (b,h) -> same-length pairs -> one CU got 2x len-32 blocks (64 iter-units,
// mean 30). Now m>=16 takes qt=15-x, m<16 takes qt=x -> paired lengths sum to 34.
// grid: (T/128=16, B=4, HEADS=7), block 256.
__global__ __launch_bounds__(256) void fano_attn(
    const short* __restrict__ Q, const short* __restrict__ K, const short* __restrict__ Vt,
    short* __restrict__ Ocat, const int* __restrict__ iscp)
{
    __shared__ short Ks[64 * 136];
    __shared__ short Vs[128 * 72];
    __shared__ short Ps[4][32 * 72];

    const int causal = *iscp;
    const int mlin = blockIdx.y + 4 * blockIdx.z;   // b + 4h in [0,28)
    const int qt = (causal && mlin >= 16) ? ((int)gridDim.x - 1 - blockIdx.x)
                                          : (int)blockIdx.x;
    const int q0 = qt * 128;
    const int b = blockIdx.y, h = blockIdx.z;
    const int tid = threadIdx.x, wave = tid >> 6, lane = tid & 63;
    const int quad = lane >> 4, l16 = lane & 15;
    const int iw = q0 + wave * 32;   // wave's min q-row

    const short* Qb = Q + (size_t)(h * MTOT + b * TT + q0) * HDIM;
    const short* Kb = K + (size_t)(h * MTOT + b * TT) * HDIM;
    const short* Vb = Vt + (size_t)h * MTOT * HDIM + (size_t)b * HDIM * TT;

    // Q fragments direct from global (scale*log2e folded at projection)
    bf16x8 qf[2][4];
    for (int g = 0; g < 2; g++)
        for (int ks = 0; ks < 4; ks++)
            qf[g][ks] = *(const bf16x8*)(Qb + (size_t)(wave * 32 + g * 16 + l16) * HDIM + ks * 32 + quad * 8);

    f32x4 oacc[2][8] = {};
    f32x4 lacc[2] = {};
    int irow[2][4];
    for (int g = 0; g < 2; g++)
        for (int r = 0; r < 4; r++)
            irow[g][r] = q0 + wave * 32 + g * 16 + quad * 4 + r;

    const bf16x8 vones = {0x3F80, 0x3F80, 0x3F80, 0x3F80, 0x3F80, 0x3F80, 0x3F80, 0x3F80};

    // staging maps (16B chunks, 4 per thread per tile)
    int krow[4], kcol[4], vrow[4], vcol[4];
    for (int i = 0; i < 4; i++) {
        int c = tid + i * 256;
        krow[i] = c >> 4; kcol[i] = (c & 15) * 8;
        vrow[i] = c >> 3; vcol[i] = (c & 7) * 8;
    }

    const int send = causal ? (q0 + 128) : TT;

    bf16x8 kreg[4], vreg[4];
    for (int i = 0; i < 4; i++) {
        kreg[i] = *(const bf16x8*)(Kb + (size_t)krow[i] * HDIM + kcol[i]);
        vreg[i] = *(const bf16x8*)(Vb + (size_t)vrow[i] * TT + vcol[i]);
    }

    int d7b = (l16 - h + 7) % 7;   // (s - h) mod 7 at s = s0 + l16
    short* Pw = &Ps[wave][0];

    for (int s0 = 0; s0 < send; s0 += 64) {
        __syncthreads();
        for (int i = 0; i < 4; i++) {
            *(bf16x8*)(Ks + krow[i] * 136 + kcol[i]) = kreg[i];
            *(bf16x8*)(Vs + vrow[i] * 72 + vcol[i]) = vreg[i];
        }
        __syncthreads();

        int sn = s0 + 64; if (sn >= send) sn = s0;
        const short* Kn = Kb + (size_t)sn * HDIM;
        const short* Vn = Vb + sn;
        for (int i = 0; i < 4; i++) {
            kreg[i] = *(const bf16x8*)(Kn + (size_t)krow[i] * HDIM + kcol[i]);
            vreg[i] = *(const bf16x8*)(Vn + (size_t)vrow[i] * TT + vcol[i]);
        }

        // S = Q K^T (log2 domain)
        f32x4 sacc[2][4] = {};
        for (int ni = 0; ni < 4; ni++)
            for (int ks = 0; ks < 4; ks++) {
                bf16x8 bk = *(const bf16x8*)(Ks + (ni * 16 + l16) * 136 + ks * 32 + quad * 8);
                sacc[0][ni] = __builtin_amdgcn_mfma_f32_16x16x32_bf16(qf[0][ks], bk, sacc[0][ni], 0, 0, 0);
                sacc[1][ni] = __builtin_amdgcn_mfma_f32_16x16x32_bf16(qf[1][ks], bk, sacc[1][ni], 0, 0, 0);
            }

        // mask + exp2 (static base: no max tracking, no rescale)
        const bool full = (s0 + 80 > iw) && (causal || (s0 < iw + 48));
        if (full) {
            for (int ni = 0; ni < 4; ni++) {
                int d7 = d7b + 2 * ni; if (d7 >= 7) d7 -= 7;
                bool line = (0x0B >> d7) & 1;
                int s = s0 + ni * 16 + l16;
                for (int g = 0; g < 2; g++)
                    for (int r = 0; r < 4; r++) {
                        int i = irow[g][r];
                        bool ok = causal ? ((s <= i) & (line | (s >= i - 16)))
                                         : (line | ((s >= i - 16) & (s <= i + 16)));
                        sacc[g][ni][r] = ok ? exp2f(sacc[g][ni][r]) : 0.0f;
                    }
            }
        } else {
            for (int ni = 0; ni < 4; ni++) {
                int d7 = d7b + 2 * ni; if (d7 >= 7) d7 -= 7;
                bool line = (0x0B >> d7) & 1;
                for (int g = 0; g < 2; g++)
                    for (int r = 0; r < 4; r++)
                        sacc[g][ni][r] = line ? exp2f(sacc[g][ni][r]) : 0.0f;
            }
        }
        d7b++; if (d7b == 7) d7b = 0;

        // P: C-layout regs -> wave-private LDS (both groups) -> A-layout frags
        for (int g = 0; g < 2; g++)
            for (int ni = 0; ni < 4; ni++)
                for (int r = 0; r < 4; r++)
                    Pw[(g * 16 + quad * 4 + r) * 72 + ni * 16 + l16] = f2bf(sacc[g][ni][r]);

        // O += P V ; row-sums via ones-column MFMA
        for (int ks2 = 0; ks2 < 2; ks2++) {
            bf16x8 ap0 = *(const bf16x8*)(Pw + l16 * 72 + ks2 * 32 + quad * 8);
            bf16x8 ap1 = *(const bf16x8*)(Pw + (16 + l16) * 72 + ks2 * 32 + quad * 8);
            lacc[0] = __builtin_amdgcn_mfma_f32_16x16x32_bf16(ap0, vones, lacc[0], 0, 0, 0);
            lacc[1] = __builtin_amdgcn_mfma_f32_16x16x32_bf16(ap1, vones, lacc[1], 0, 0, 0);
            for (int nj = 0; nj < 8; nj++) {
                bf16x8 bv = *(const bf16x8*)(Vs + (nj * 16 + l16) * 72 + ks2 * 32 + quad * 8);
                oacc[0][nj] = __builtin_amdgcn_mfma_f32_16x16x32_bf16(ap0, bv, oacc[0][nj], 0, 0, 0);
                oacc[1][nj] = __builtin_amdgcn_mfma_f32_16x16x32_bf16(ap1, bv, oacc[1][nj], 0, 0, 0);
            }
        }
    }

    short* Obase = Ocat + (size_t)(b * TT) * HIDDEN + h * HDIM;
    for (int g = 0; g < 2; g++) {
        float inv[4];
        for (int r = 0; r < 4; r++) inv[r] = 1.0f / lacc[g][r];
        for (int nj = 0; nj < 8; nj++)
            for (int r = 0; r < 4; r++)
                Obase[(size_t)irow[g][r] * HIDDEN + nj * 16 + l16] = f2bf(oacc[g][nj][r] * inv[r]);
    }
}

// ---------------- kernel 4: output projection (128x128 tile) ----------------
__global__ __launch_bounds__(256) void out_gemm(
    const short* __restrict__ A, const short* __restrict__ Bt, float* __restrict__ out)
{
    __shared__ short Ash[128 * 40];
    __shared__ short Bsh[128 * 40];
    const int m0 = blockIdx.x * 128;
    const int n0 = blockIdx.y * 128;

    const int tid = threadIdx.x;
    const int wave = tid >> 6, lane = tid & 63;
    const int quad = lane >> 4, l16 = lane & 15;
    const int wm = (wave >> 1) * 64, wn = (wave & 1) * 64;

    f32x4 acc[4][4] = {};
    const int sr = tid >> 2, sc = (tid & 3) * 8;

    for (int k0 = 0; k0 < HIDDEN; k0 += 32) {
        bf16x8 a0 = *(const bf16x8*)(A + (size_t)(m0 + sr) * HIDDEN + k0 + sc);
        bf16x8 a1 = *(const bf16x8*)(A + (size_t)(m0 + sr + 64) * HIDDEN + k0 + sc);
        bf16x8 b0 = *(const bf16x8*)(Bt + (size_t)(n0 + sr) * HIDDEN + k0 + sc);
        bf16x8 b1 = *(const bf16x8*)(Bt + (size_t)(n0 + sr + 64) * HIDDEN + k0 + sc);
        __syncthreads();
        *(bf16x8*)(Ash + sr * 40 + sc) = a0;
        *(bf16x8*)(Ash + (sr + 64) * 40 + sc) = a1;
        *(bf16x8*)(Bsh + sr * 40 + sc) = b0;
        *(bf16x8*)(Bsh + (sr + 64) * 40 + sc) = b1;
        __syncthreads();
        bf16x8 af[4], bfr[4];
        for (int mi = 0; mi < 4; mi++)
            af[mi] = *(const bf16x8*)(Ash + (wm + mi * 16 + l16) * 40 + quad * 8);
        for (int ni = 0; ni < 4; ni++)
            bfr[ni] = *(const bf16x8*)(Bsh + (wn + ni * 16 + l16) * 40 + quad * 8);
        for (int mi = 0; mi < 4; mi++)
            for (int ni = 0; ni < 4; ni++)
                acc[mi][ni] = __builtin_amdgcn_mfma_f32_16x16x32_bf16(af[mi], bfr[ni], acc[mi][ni], 0, 0, 0);
    }

    for (int mi = 0; mi < 4; mi++)
        for (int ni = 0; ni < 4; ni++)
            for (int r = 0; r < 4; r++) {
                int m = m0 + wm + mi * 16 + quad * 4 + r;
                int n = n0 + wn + ni * 16 + l16;
                out[(size_t)m * HIDDEN + n] = acc[mi][ni][r];
            }
}

extern "C" void kernel_launch(void* const* d_in, const int* in_sizes, int n_in,
                              void* d_out, int out_size, void* d_ws, size_t ws_size,
                              hipStream_t stream) {
    (void)in_sizes; (void)n_in; (void)out_size; (void)ws_size;
    const float* x  = (const float*)d_in[0];
    const float* Wq = (const float*)d_in[1];
    const float* Wk = (const float*)d_in[2];
    const float* Wv = (const float*)d_in[3];
    const float* Wo = (const float*)d_in[4];
    const int* iscp = (const int*)d_in[5];
    float* out = (float*)d_out;

    short* xb   = (short*)d_ws;                       // 8192*896
    short* Qb   = xb   + (size_t)MTOT * HIDDEN;       // 7*8192*128 each
    short* Kb   = Qb   + (size_t)HEADS * MTOT * HDIM;
    short* Vtb  = Kb   + (size_t)HEADS * MTOT * HDIM;
    short* Ocat = Vtb  + (size_t)HEADS * MTOT * HDIM; // 8192*896 (aliased with Wt)
    short* Wt   = Ocat;                               // 21*128*896, used only before attn
    short* Wob  = Ocat + (size_t)MTOT * HIDDEN;       // 896*896

    cast_x_kernel<<<(MTOT * HIDDEN) / (256 * 4), 256, 0, stream>>>(x, xb);
    cast_wo_kernel<<<(HIDDEN * HIDDEN) / (256 * 4), 256, 0, stream>>>(Wo, Wob);
    transpose_cast_w<<<dim3(HIDDEN / 32, HDIM / 32, 21), 256, 0, stream>>>(Wq, Wk, Wv, Wt);
    qkv_gemm<<<dim3(MTOT / 128, 21), 256, 0, stream>>>(xb, Wt, Qb, Kb, Vtb);
    fano_attn<<<dim3(TT / 128, BB, HEADS), 256, 0, stream>>>(Qb, Kb, Vtb, Ocat, iscp);
    out_gemm<<<dim3(MTOT / 128, HIDDEN / 128), 256, 0, stream>>>(Ocat, Wob, out);
}

// Round 9
// 341.821 us; speedup vs baseline: 1.6379x; 1.0075x over previous
//
#include <hip/hip_runtime.h>
#include <hip/hip_bf16.h>

#define HIDDEN 896
#define HEADS 7
#define HDIM 128
#define BB 4
#define TT 2048
#define MTOT (BB*TT)   // 8192

typedef short bf16x8 __attribute__((ext_vector_type(8)));
typedef float f32x4 __attribute__((ext_vector_type(4)));

__device__ __forceinline__ short f2bf(float f) {
    union { float f; unsigned u; } v; v.f = f;
    unsigned r = (v.u + 0x7FFF + ((v.u >> 16) & 1)) >> 16;
    return (short)r;
}

// async global->LDS, 16B per lane; lds dst must be wave-uniform base (+lane*16 implicit)
__device__ __forceinline__ void gll16(const short* g, short* l) {
    __builtin_amdgcn_global_load_lds(
        (const __attribute__((address_space(1))) unsigned int*)g,
        (__attribute__((address_space(3))) unsigned int*)l, 16, 0, 0);
}

// ---------------- kernel 1: cast x (fp32) -> bf16 ----------------
__global__ __launch_bounds__(256) void cast_x_kernel(const float* __restrict__ x,
                                                     short* __restrict__ xb) {
    int base = (blockIdx.x * 256 + threadIdx.x) * 4;
    if (base < MTOT * HIDDEN) {
        float4 v = *(const float4*)(x + base);
        short4 o;
        o.x = f2bf(v.x); o.y = f2bf(v.y); o.z = f2bf(v.z); o.w = f2bf(v.w);
        *(short4*)(xb + base) = o;
    }
}

// cast Wo fp32[896][896] -> bf16 (already B^T form [n][k])
__global__ __launch_bounds__(256) void cast_wo_kernel(const float* __restrict__ src,
                                                      short* __restrict__ dst) {
    int base = (blockIdx.x * 256 + threadIdx.x) * 4;
    if (base < HIDDEN * HIDDEN) {
        float4 v = *(const float4*)(src + base);
        short4 o;
        o.x = f2bf(v.x); o.y = f2bf(v.y); o.z = f2bf(v.z); o.w = f2bf(v.w);
        *(short4*)(dst + base) = o;
    }
}

// transpose-cast Wq/Wk/Wv fp32 [head][896 k][128 n] -> bf16 Wt[type*7+head][128 n][896 k]
__global__ __launch_bounds__(256) void transpose_cast_w(
    const float* __restrict__ Wq, const float* __restrict__ Wk,
    const float* __restrict__ Wv, short* __restrict__ Wt)
{
    __shared__ float tile[32][33];
    const int z = blockIdx.z;
    const int type = z / 7, head = z % 7;
    const float* src = (type == 0 ? Wq : (type == 1 ? Wk : Wv)) + head * (HIDDEN * HDIM);
    short* dst = Wt + (size_t)z * (HDIM * HIDDEN);
    const int r0 = blockIdx.x * 32, c0 = blockIdx.y * 32;
    const int tx = threadIdx.x & 31, ty = threadIdx.x >> 5;  // 32 x 8
    for (int i = 0; i < 4; i++)
        tile[ty * 4 + i][tx] = src[(r0 + ty * 4 + i) * HDIM + c0 + tx];
    __syncthreads();
    for (int i = 0; i < 4; i++)
        dst[(c0 + ty * 4 + i) * HIDDEN + r0 + tx] = f2bf(tile[tx][ty * 4 + i]);
}

// ---------------- kernel 2: QKV projection GEMM (128x128, global_load_lds) ----------------
// m97-style staging: unpadded [128][32] LDS tiles, layout == chunk-id*16B so the
// wave-uniform-base + lane*16 DMA constraint is satisfied. 2 calls/operand/k-step.
__global__ __launch_bounds__(256) void qkv_gemm(
    const short* __restrict__ xb, const short* __restrict__ Wt,
    short* __restrict__ Q, short* __restrict__ Kk, short* __restrict__ Vt)
{
    __shared__ short Ash[128 * 32];
    __shared__ short Bsh[128 * 32];
    const int m0 = blockIdx.x * 128;
    const int z = blockIdx.y;
    const int head = z % 7, type = z / 7;
    const short* Wz = Wt + (size_t)z * (HDIM * HIDDEN);

    const int tid = threadIdx.x;
    const int wave = tid >> 6, lane = tid & 63;
    const int quad = lane >> 4, l16 = lane & 15;
    const int wm = (wave >> 1) * 64, wn = (wave & 1) * 64;

    f32x4 acc[4][4] = {};

    // chunk mapping: chunk c -> row c>>2, colchunk (c&3)*8; call0 c=tid (rows 0-63),
    // call1 c=tid+256 (rows 64-127). LDS offset of chunk c = c*8 shorts.
    const int r0 = tid >> 2, cc0 = (tid & 3) * 8;
    const int r1 = r0 + 64;
    short* adst0 = Ash + wave * 512;
    short* adst1 = Ash + 2048 + wave * 512;
    short* bdst0 = Bsh + wave * 512;
    short* bdst1 = Bsh + 2048 + wave * 512;
    const short* asrc0 = xb + (size_t)(m0 + r0) * HIDDEN + cc0;
    const short* asrc1 = xb + (size_t)(m0 + r1) * HIDDEN + cc0;
    const short* bsrc0 = Wz + (size_t)r0 * HIDDEN + cc0;
    const short* bsrc1 = Wz + (size_t)r1 * HIDDEN + cc0;

    for (int k0 = 0; k0 < HIDDEN; k0 += 32) {
        __syncthreads();                 // prev tile fully consumed
        gll16(asrc0 + k0, adst0);
        gll16(asrc1 + k0, adst1);
        gll16(bsrc0 + k0, bdst0);
        gll16(bsrc1 + k0, bdst1);
        __syncthreads();                 // drains vmcnt -> LDS tile ready
        bf16x8 af[4], bfr[4];
        for (int mi = 0; mi < 4; mi++)
            af[mi] = *(const bf16x8*)(Ash + (wm + mi * 16 + l16) * 32 + quad * 8);
        for (int ni = 0; ni < 4; ni++)
            bfr[ni] = *(const bf16x8*)(Bsh + (wn + ni * 16 + l16) * 32 + quad * 8);
        for (int mi = 0; mi < 4; mi++)
            for (int ni = 0; ni < 4; ni++)
                acc[mi][ni] = __builtin_amdgcn_mfma_f32_16x16x32_bf16(af[mi], bfr[ni], acc[mi][ni], 0, 0, 0);
    }

    const size_t base = (size_t)head * (MTOT * HDIM);
    if (type == 0) {
        // fold softmax scale AND log2(e) into Q (softmax done in exp2 domain)
        const float qs = 0.08838834764831845f * 1.4426950408889634f;
        for (int mi = 0; mi < 4; mi++)
            for (int ni = 0; ni < 4; ni++)
                for (int r = 0; r < 4; r++) {
                    int m = m0 + wm + mi * 16 + quad * 4 + r;
                    int n = wn + ni * 16 + l16;
                    Q[base + (size_t)m * HDIM + n] = f2bf(acc[mi][ni][r] * qs);
                }
    } else if (type == 1) {
        for (int mi = 0; mi < 4; mi++)
            for (int ni = 0; ni < 4; ni++)
                for (int r = 0; r < 4; r++) {
                    int m = m0 + wm + mi * 16 + quad * 4 + r;
                    int n = wn + ni * 16 + l16;
                    Kk[base + (size_t)m * HDIM + n] = f2bf(acc[mi][ni][r]);
                }
    } else {
        for (int mi = 0; mi < 4; mi++)
            for (int ni = 0; ni < 4; ni++) {
                int m = m0 + wm + mi * 16 + quad * 4;
                int bb = m >> 11, t = m & 2047;
                int n = wn + ni * 16 + l16;
                short4 o;
                o.x = f2bf(acc[mi][ni][0]); o.y = f2bf(acc[mi][ni][1]);
                o.z = f2bf(acc[mi][ni][2]); o.w = f2bf(acc[mi][ni][3]);
                *(short4*)(Vt + base + (size_t)bb * (HDIM * TT) + (size_t)n * TT + t) = o;
            }
    }
}

// ---------------- kernel 3: fano flash attention v8 (unchanged from r8) ----------------
__global__ __launch_bounds__(256) void fano_attn(
    const short* __restrict__ Q, const short* __restrict__ K, const short* __restrict__ Vt,
    short* __restrict__ Ocat, const int* __restrict__ iscp)
{
    __shared__ short Ks[64 * 136];
    __shared__ short Vs[128 * 72];
    __shared__ short Ps[4][32 * 72];

    const int causal = *iscp;
    const int mlin = blockIdx.y + 4 * blockIdx.z;   // b + 4h in [0,28)
    const int qt = (causal && mlin >= 16) ? ((int)gridDim.x - 1 - blockIdx.x)
                                          : (int)blockIdx.x;
    const int q0 = qt * 128;
    const int b = blockIdx.y, h = blockIdx.z;
    const int tid = threadIdx.x, wave = tid >> 6, lane = tid & 63;
    const int quad = lane >> 4, l16 = lane & 15;
    const int iw = q0 + wave * 32;   // wave's min q-row

    const short* Qb = Q + (size_t)(h * MTOT + b * TT + q0) * HDIM;
    const short* Kb = K + (size_t)(h * MTOT + b * TT) * HDIM;
    const short* Vb = Vt + (size_t)h * MTOT * HDIM + (size_t)b * HDIM * TT;

    bf16x8 qf[2][4];
    for (int g = 0; g < 2; g++)
        for (int ks = 0; ks < 4; ks++)
            qf[g][ks] = *(const bf16x8*)(Qb + (size_t)(wave * 32 + g * 16 + l16) * HDIM + ks * 32 + quad * 8);

    f32x4 oacc[2][8] = {};
    f32x4 lacc[2] = {};
    int irow[2][4];
    for (int g = 0; g < 2; g++)
        for (int r = 0; r < 4; r++)
            irow[g][r] = q0 + wave * 32 + g * 16 + quad * 4 + r;

    const bf16x8 vones = {0x3F80, 0x3F80, 0x3F80, 0x3F80, 0x3F80, 0x3F80, 0x3F80, 0x3F80};

    int krow[4], kcol[4], vrow[4], vcol[4];
    for (int i = 0; i < 4; i++) {
        int c = tid + i * 256;
        krow[i] = c >> 4; kcol[i] = (c & 15) * 8;
        vrow[i] = c >> 3; vcol[i] = (c & 7) * 8;
    }

    const int send = causal ? (q0 + 128) : TT;

    bf16x8 kreg[4], vreg[4];
    for (int i = 0; i < 4; i++) {
        kreg[i] = *(const bf16x8*)(Kb + (size_t)krow[i] * HDIM + kcol[i]);
        vreg[i] = *(const bf16x8*)(Vb + (size_t)vrow[i] * TT + vcol[i]);
    }

    int d7b = (l16 - h + 7) % 7;
    short* Pw = &Ps[wave][0];

    for (int s0 = 0; s0 < send; s0 += 64) {
        __syncthreads();
        for (int i = 0; i < 4; i++) {
            *(bf16x8*)(Ks + krow[i] * 136 + kcol[i]) = kreg[i];
            *(bf16x8*)(Vs + vrow[i] * 72 + vcol[i]) = vreg[i];
        }
        __syncthreads();

        int sn = s0 + 64; if (sn >= send) sn = s0;
        const short* Kn = Kb + (size_t)sn * HDIM;
        const short* Vn = Vb + sn;
        for (int i = 0; i < 4; i++) {
            kreg[i] = *(const bf16x8*)(Kn + (size_t)krow[i] * HDIM + kcol[i]);
            vreg[i] = *(const bf16x8*)(Vn + (size_t)vrow[i] * TT + vcol[i]);
        }

        f32x4 sacc[2][4] = {};
        for (int ni = 0; ni < 4; ni++)
            for (int ks = 0; ks < 4; ks++) {
                bf16x8 bk = *(const bf16x8*)(Ks + (ni * 16 + l16) * 136 + ks * 32 + quad * 8);
                sacc[0][ni] = __builtin_amdgcn_mfma_f32_16x16x32_bf16(qf[0][ks], bk, sacc[0][ni], 0, 0, 0);
                sacc[1][ni] = __builtin_amdgcn_mfma_f32_16x16x32_bf16(qf[1][ks], bk, sacc[1][ni], 0, 0, 0);
            }

        const bool full = (s0 + 80 > iw) && (causal || (s0 < iw + 48));
        if (full) {
            for (int ni = 0; ni < 4; ni++) {
                int d7 = d7b + 2 * ni; if (d7 >= 7) d7 -= 7;
                bool line = (0x0B >> d7) & 1;
                int s = s0 + ni * 16 + l16;
                for (int g = 0; g < 2; g++)
                    for (int r = 0; r < 4; r++) {
                        int i = irow[g][r];
                        bool ok = causal ? ((s <= i) & (line | (s >= i - 16)))
                                         : (line | ((s >= i - 16) & (s <= i + 16)));
                        sacc[g][ni][r] = ok ? exp2f(sacc[g][ni][r]) : 0.0f;
                    }
            }
        } else {
            for (int ni = 0; ni < 4; ni++) {
                int d7 = d7b + 2 * ni; if (d7 >= 7) d7 -= 7;
                bool line = (0x0B >> d7) & 1;
                for (int g = 0; g < 2; g++)
                    for (int r = 0; r < 4; r++)
                        sacc[g][ni][r] = line ? exp2f(sacc[g][ni][r]) : 0.0f;
            }
        }
        d7b++; if (d7b == 7) d7b = 0;

        for (int g = 0; g < 2; g++)
            for (int ni = 0; ni < 4; ni++)
                for (int r = 0; r < 4; r++)
                    Pw[(g * 16 + quad * 4 + r) * 72 + ni * 16 + l16] = f2bf(sacc[g][ni][r]);

        for (int ks2 = 0; ks2 < 2; ks2++) {
            bf16x8 ap0 = *(const bf16x8*)(Pw + l16 * 72 + ks2 * 32 + quad * 8);
            bf16x8 ap1 = *(const bf16x8*)(Pw + (16 + l16) * 72 + ks2 * 32 + quad * 8);
            lacc[0] = __builtin_amdgcn_mfma_f32_16x16x32_bf16(ap0, vones, lacc[0], 0, 0, 0);
            lacc[1] = __builtin_amdgcn_mfma_f32_16x16x32_bf16(ap1, vones, lacc[1], 0, 0, 0);
            for (int nj = 0; nj < 8; nj++) {
                bf16x8 bv = *(const bf16x8*)(Vs + (nj * 16 + l16) * 72 + ks2 * 32 + quad * 8);
                oacc[0][nj] = __builtin_amdgcn_mfma_f32_16x16x32_bf16(ap0, bv, oacc[0][nj], 0, 0, 0);
                oacc[1][nj] = __builtin_amdgcn_mfma_f32_16x16x32_bf16(ap1, bv, oacc[1][nj], 0, 0, 0);
            }
        }
    }

    short* Obase = Ocat + (size_t)(b * TT) * HIDDEN + h * HDIM;
    for (int g = 0; g < 2; g++) {
        float inv[4];
        for (int r = 0; r < 4; r++) inv[r] = 1.0f / lacc[g][r];
        for (int nj = 0; nj < 8; nj++)
            for (int r = 0; r < 4; r++)
                Obase[(size_t)irow[g][r] * HIDDEN + nj * 16 + l16] = f2bf(oacc[g][nj][r] * inv[r]);
    }
}

// ---------------- kernel 4: output projection (128x128, global_load_lds) ----------------
__global__ __launch_bounds__(256) void out_gemm(
    const short* __restrict__ A, const short* __restrict__ Bt, float* __restrict__ out)
{
    __shared__ short Ash[128 * 32];
    __shared__ short Bsh[128 * 32];
    const int m0 = blockIdx.x * 128;
    const int n0 = blockIdx.y * 128;

    const int tid = threadIdx.x;
    const int wave = tid >> 6, lane = tid & 63;
    const int quad = lane >> 4, l16 = lane & 15;
    const int wm = (wave >> 1) * 64, wn = (wave & 1) * 64;

    f32x4 acc[4][4] = {};

    const int r0 = tid >> 2, cc0 = (tid & 3) * 8;
    const int r1 = r0 + 64;
    short* adst0 = Ash + wave * 512;
    short* adst1 = Ash + 2048 + wave * 512;
    short* bdst0 = Bsh + wave * 512;
    short* bdst1 = Bsh + 2048 + wave * 512;
    const short* asrc0 = A + (size_t)(m0 + r0) * HIDDEN + cc0;
    const short* asrc1 = A + (size_t)(m0 + r1) * HIDDEN + cc0;
    const short* bsrc0 = Bt + (size_t)(n0 + r0) * HIDDEN + cc0;
    const short* bsrc1 = Bt + (size_t)(n0 + r1) * HIDDEN + cc0;

    for (int k0 = 0; k0 < HIDDEN; k0 += 32) {
        __syncthreads();
        gll16(asrc0 + k0, adst0);
        gll16(asrc1 + k0, adst1);
        gll16(bsrc0 + k0, bdst0);
        gll16(bsrc1 + k0, bdst1);
        __syncthreads();
        bf16x8 af[4], bfr[4];
        for (int mi = 0; mi < 4; mi++)
            af[mi] = *(const bf16x8*)(Ash + (wm + mi * 16 + l16) * 32 + quad * 8);
        for (int ni = 0; ni < 4; ni++)
            bfr[ni] = *(const bf16x8*)(Bsh + (wn + ni * 16 + l16) * 32 + quad * 8);
        for (int mi = 0; mi < 4; mi++)
            for (int ni = 0; ni < 4; ni++)
                acc[mi][ni] = __builtin_amdgcn_mfma_f32_16x16x32_bf16(af[mi], bfr[ni], acc[mi][ni], 0, 0, 0);
    }

    for (int mi = 0; mi < 4; mi++)
        for (int ni = 0; ni < 4; ni++)
            for (int r = 0; r < 4; r++) {
                int m = m0 + wm + mi * 16 + quad * 4 + r;
                int n = n0 + wn + ni * 16 + l16;
                out[(size_t)m * HIDDEN + n] = acc[mi][ni][r];
            }
}

extern "C" void kernel_launch(void* const* d_in, const int* in_sizes, int n_in,
                              void* d_out, int out_size, void* d_ws, size_t ws_size,
                              hipStream_t stream) {
    (void)in_sizes; (void)n_in; (void)out_size; (void)ws_size;
    const float* x  = (const float*)d_in[0];
    const float* Wq = (const float*)d_in[1];
    const float* Wk = (const float*)d_in[2];
    const float* Wv = (const float*)d_in[3];
    const float* Wo = (const float*)d_in[4];
    const int* iscp = (const int*)d_in[5];
    float* out = (float*)d_out;

    short* xb   = (short*)d_ws;                       // 8192*896
    short* Qb   = xb   + (size_t)MTOT * HIDDEN;       // 7*8192*128 each
    short* Kb   = Qb   + (size_t)HEADS * MTOT * HDIM;
    short* Vtb  = Kb   + (size_t)HEADS * MTOT * HDIM;
    short* Ocat = Vtb  + (size_t)HEADS * MTOT * HDIM; // 8192*896 (aliased with Wt)
    short* Wt   = Ocat;                               // 21*128*896, used only before attn
    short* Wob  = Ocat + (size_t)MTOT * HIDDEN;       // 896*896

    cast_x_kernel<<<(MTOT * HIDDEN) / (256 * 4), 256, 0, stream>>>(x, xb);
    cast_wo_kernel<<<(HIDDEN * HIDDEN) / (256 * 4), 256, 0, stream>>>(Wo, Wob);
    transpose_cast_w<<<dim3(HIDDEN / 32, HDIM / 32, 21), 256, 0, stream>>>(Wq, Wk, Wv, Wt);
    qkv_gemm<<<dim3(MTOT / 128, 21), 256, 0, stream>>>(xb, Wt, Qb, Kb, Vtb);
    fano_attn<<<dim3(TT / 128, BB, HEADS), 256, 0, stream>>>(Qb, Kb, Vtb, Ocat, iscp);
    out_gemm<<<dim3(MTOT / 128, HIDDEN / 128), 256, 0, stream>>>(Ocat, Wob, out);
}